// Round 17
// baseline (357.232 us; speedup 1.0000x reference)
//
#include <hip/hip_runtime.h>

// WKV7 (RWKV-7) forward scan. T=2048, H=64, D=64.
// R17 = R16 + 2-deep software-pipelined reduce. The quad_reduce's 8-level
// dependent DPP chain was R16's remaining in-body stall (~145 cyc): its
// inputs (partials) were computed ~10 instr before, its output consumed
// ~14 instr after. Now partials for step t+1 are computed at body t-1 END
// (they need only S_{t-1}, e_t, b_t, k_t, a_{t+1} -- a_{t+1} comes from the
// nx2 ds_read of that same body), and quad_reduce runs at body t TOP on
// pure registers, overlapping the ds_read/vmcnt phase. Carried chain per
// body: compose (2 fma) -> update (3 fma) -> partials (2 fma lvls) ->
// [body boundary] -> reduce (padded) -> compose. Every hop has >=25 cyc of
// independent padding.
//   sa_{t+1} = R2 + beta*sa_t + gamma*vv_t
//     R2 = sum_j S_{t-1}[j] e_t[j] a_{t+1}[j], beta = b_t.a_{t+1},
//     gamma = k_t.a_{t+1}
// Memory machinery = R14/R16: width-16 2-op global_load_lds staging, 8-slot
// ring, vmcnt(10) guard, y-store batched 8x, 1024 blocks x 64 thr.

typedef float f32x4 __attribute__((ext_vector_type(4)));

constexpr int T_LEN = 2048;
constexpr int DD    = 64;
constexpr int HD    = 64 * 64;   // 4096

#define AS1 __attribute__((address_space(1)))
#define AS3 __attribute__((address_space(3)))

struct Buf  { f32x4 r, e, k, a, b; float vv; };
struct Quad { float r2, bb, gg, yy; };   // named scalars (rule #20)

__global__ __launch_bounds__(256)
void exp_kernel(const float4* __restrict__ w, float4* __restrict__ ew, int n4) {
  int i = blockIdx.x * blockDim.x + threadIdx.x;
  int stride = gridDim.x * blockDim.x;
  for (; i < n4; i += stride) {
    float4 x = w[i];
    float4 o;
    o.x = __expf(x.x); o.y = __expf(x.y); o.z = __expf(x.z); o.w = __expf(x.w);
    ew[i] = o;
  }
}

template<int CTRL>
__device__ __forceinline__ float dpp_add(float x) {
  int y = __builtin_amdgcn_update_dpp(0, __float_as_int(x), CTRL, 0xf, 0xf, true);
  return x + __int_as_float(y);
}

// Serial 16-lane reduce (prologue/epilogue only).
__device__ __forceinline__ float row16_reduce(float x) {
  x = dpp_add<0xB1>(x);    // quad_perm [1,0,3,2]
  x = dpp_add<0x4E>(x);    // quad_perm [2,3,0,1]
  x = dpp_add<0x141>(x);   // row_half_mirror
  x = dpp_add<0x140>(x);   // row_mirror
  return x;
}

// FOUR interleaved row-of-16 reductions (verified R10/R16). Dependent ops
// >=3 apart (needs 2); s_nop 1 covers the entry hazard (R8 lesson).
__device__ __forceinline__ void quad_reduce(float& a, float& b, float& c, float& d) {
  float t0, t1, t2, t3;
  asm volatile(
    "s_nop 1\n\t"
    "v_mov_b32_dpp %4, %0 quad_perm:[1,0,3,2] row_mask:0xf bank_mask:0xf\n\t"
    "v_mov_b32_dpp %5, %1 quad_perm:[1,0,3,2] row_mask:0xf bank_mask:0xf\n\t"
    "v_mov_b32_dpp %6, %2 quad_perm:[1,0,3,2] row_mask:0xf bank_mask:0xf\n\t"
    "v_mov_b32_dpp %7, %3 quad_perm:[1,0,3,2] row_mask:0xf bank_mask:0xf\n\t"
    "v_add_f32 %0, %0, %4\n\t"
    "v_add_f32 %1, %1, %5\n\t"
    "v_add_f32 %2, %2, %6\n\t"
    "v_add_f32 %3, %3, %7\n\t"
    "v_mov_b32_dpp %4, %0 quad_perm:[2,3,0,1] row_mask:0xf bank_mask:0xf\n\t"
    "v_mov_b32_dpp %5, %1 quad_perm:[2,3,0,1] row_mask:0xf bank_mask:0xf\n\t"
    "v_mov_b32_dpp %6, %2 quad_perm:[2,3,0,1] row_mask:0xf bank_mask:0xf\n\t"
    "v_mov_b32_dpp %7, %3 quad_perm:[2,3,0,1] row_mask:0xf bank_mask:0xf\n\t"
    "v_add_f32 %0, %0, %4\n\t"
    "v_add_f32 %1, %1, %5\n\t"
    "v_add_f32 %2, %2, %6\n\t"
    "v_add_f32 %3, %3, %7\n\t"
    "v_mov_b32_dpp %4, %0 row_half_mirror row_mask:0xf bank_mask:0xf\n\t"
    "v_mov_b32_dpp %5, %1 row_half_mirror row_mask:0xf bank_mask:0xf\n\t"
    "v_mov_b32_dpp %6, %2 row_half_mirror row_mask:0xf bank_mask:0xf\n\t"
    "v_mov_b32_dpp %7, %3 row_half_mirror row_mask:0xf bank_mask:0xf\n\t"
    "v_add_f32 %0, %0, %4\n\t"
    "v_add_f32 %1, %1, %5\n\t"
    "v_add_f32 %2, %2, %6\n\t"
    "v_add_f32 %3, %3, %7\n\t"
    "v_mov_b32_dpp %4, %0 row_mirror row_mask:0xf bank_mask:0xf\n\t"
    "v_mov_b32_dpp %5, %1 row_mirror row_mask:0xf bank_mask:0xf\n\t"
    "v_mov_b32_dpp %6, %2 row_mirror row_mask:0xf bank_mask:0xf\n\t"
    "v_mov_b32_dpp %7, %3 row_mirror row_mask:0xf bank_mask:0xf\n\t"
    "v_add_f32 %0, %0, %4\n\t"
    "v_add_f32 %1, %1, %5\n\t"
    "v_add_f32 %2, %2, %6\n\t"
    "v_add_f32 %3, %3, %7"
    : "+v"(a), "+v"(b), "+v"(c), "+v"(d),
      "=&v"(t0), "=&v"(t1), "=&v"(t2), "=&v"(t3));
}

__device__ __forceinline__ float dot4(const f32x4& x, const f32x4& y) {
  return fmaf(x[3], y[3], fmaf(x[2], y[2], fmaf(x[1], y[1], x[0] * y[0])));
}

__device__ __forceinline__ void gload_lds16(const float* g, const float* l) {
  __builtin_amdgcn_global_load_lds((const AS1 unsigned*)g, (AS3 unsigned*)l, 16, 0, 0);
}

__global__ __launch_bounds__(64, 1)
void wkv7_scan(const float* __restrict__ R, const float* __restrict__ EW,
               const float* __restrict__ K, const float* __restrict__ V,
               const float* __restrict__ A, const float* __restrict__ B,
               const float* __restrict__ S0, float* __restrict__ X,
               float* __restrict__ SOUT)
{
  // 8 slots x 512 floats (2KB: R|EW|K|A | B|V|pad) = 16 KB
  __shared__ float smem[4096];

  const int blk = blockIdx.x;          // 0..1023
  const int xcd = blk & 7;
  const int m   = blk >> 3;            // 0..127
  const int h   = xcd * 8 + (m & 7);   // head 0..63
  const int br  = m >> 3;              // row block 0..15

  const int lane = threadIdx.x;        // 0..63
  const int cg   = lane & 15;          // cols [cg*4, cg*4+4)
  const int rl   = lane >> 4;          // local row 0..3
  const int row  = br * 4 + rl;        // 0..63
  const int c0   = cg * 4;

  // Staging sources (width-16 lane grouping, R14):
  const int g1   = lane >> 4;          // source-array group 0..3
  const int sub16 = lane & 15;         // 16B chunk within the 256B array
  const float* base1 = (g1 == 0) ? R : (g1 == 1) ? EW : (g1 == 2) ? K : A;
  const float* base2 = (g1 == 0) ? B : V;   // g1>=1 dups V into pad
  const float* p1 = base1 + h * DD + sub16 * 4;
  const float* p2 = base2 + h * DD + sub16 * 4;

  const unsigned lb  = (unsigned)(uintptr_t)(AS3 float*)&smem[0];
  const unsigned vab = lb + (unsigned)(cg * 16);   // vector-read base
  const unsigned vvb = lb + (unsigned)(row * 4);   // v-read base (+1280 imm)

  // y batched store: lane cg<8 stores step (t0+cg) of its row.
  const int ybo = (cg * HD + h * DD + row) * 4;

  f32x4 s;
  {
    const f32x4* sp = (const f32x4*)(S0 + (size_t)h * DD * DD + row * DD + c0);
    s = *sp;
  }

  auto stage = [&](int tt, int slot) {
    const size_t o = (size_t)tt * HD;
    const float* l = &smem[slot * 512];
    gload_lds16(p1 + o, l);          // R|EW|K|A -> slot[0..1024)B
    gload_lds16(p2 + o, l + 256);    // B|V|pad  -> slot[1024..2048)B
  };

  auto lds_read = [&](Buf& d, int slot) {
    unsigned va = vab + (unsigned)(slot * 2048);
    unsigned vv = vvb + (unsigned)(slot * 2048);
    asm volatile(
      "ds_read_b128 %0, %6\n\t"
      "ds_read_b128 %1, %6 offset:256\n\t"
      "ds_read_b128 %2, %6 offset:512\n\t"
      "ds_read_b128 %3, %6 offset:768\n\t"
      "ds_read_b128 %4, %6 offset:1024\n\t"
      "ds_read_b32  %5, %7 offset:1280"
      : "=&v"(d.r), "=&v"(d.e), "=&v"(d.k), "=&v"(d.a), "=&v"(d.b), "=&v"(d.vv)
      : "v"(va), "v"(vv) : "memory");
  };

  // Wait for THIS body's 6 ds_reads (the only outstanding DS ops at this
  // point), tied to the destination regs as a data dependency.
  auto wait_all_ds = [&](Buf& d) {
    asm volatile("s_waitcnt lgkmcnt(0)"
                 : "+v"(d.r), "+v"(d.e), "+v"(d.k), "+v"(d.a), "+v"(d.b),
                   "+v"(d.vv));
  };

  float sa;              // sa_t, ready at body t entry
  float ybatch = 0.0f;   // reduced y's, lane cg holds step (8m+cg)

  // Body t. Pin = raw partials {R2,beta,gamma} for step t+1 and y_{t-1}
  // partial, produced at body t-1. Pout = partials for step t+2 + y_t.
  auto body = [&](Buf& cur, Buf& nx1, Buf& nx2, Quad& Pin, Quad& Pout,
                  int t, bool FLUSH) {
    // stage(t+2) (issued at body t-6) resident: bodies t-5..t-1 issued
    // 10 loads + <=1 flush-store newer -> vmcnt(10).
    asm volatile("s_waitcnt vmcnt(10)" ::: "memory");
    lds_read(nx2, (t + 2) & 7);

    // ---- reduce carried partials (register-only; overlaps ds_reads) ----
    quad_reduce(Pin.r2, Pin.bb, Pin.gg, Pin.yy);

    // ---- state update for step t (sa ready since body t-1) ----
    const float vv = cur.vv;
    s[0] = fmaf(cur.e[0], s[0], fmaf(sa, cur.b[0], vv * cur.k[0]));
    s[1] = fmaf(cur.e[1], s[1], fmaf(sa, cur.b[1], vv * cur.k[1]));
    s[2] = fmaf(cur.e[2], s[2], fmaf(sa, cur.b[2], vv * cur.k[2]));
    s[3] = fmaf(cur.e[3], s[3], fmaf(sa, cur.b[3], vv * cur.k[3]));

    // ---- compose sa_{t+1} (2 fma; reduce finished ~14 instr ago) ----
    float sa1 = fmaf(Pin.bb, sa, fmaf(Pin.gg, vv, Pin.r2));

    // ---- y_t partial (updated s) ----
    float yp = dot4(s, cur.r);

    // ---- y batching: Pin.yy (reduced) = y_{t-1} -> lane (t-1)&7 ----
    ybatch = (cg == ((t + 7) & 7)) ? Pin.yy : ybatch;
    if (FLUSH) {
      if (t > 0 && cg < 8) {       // batch covers steps t-8..t-1
        int voff = (t - 8) * (HD * 4) + ybo;
        asm volatile("global_store_dword %0, %1, %2"
                     :: "v"(voff), "v"(ybatch), "s"(X) : "memory");
      }
    }

    stage((t + 8) & (T_LEN - 1), t & 7);

    // ---- partials for step t+2 (need nx2.a -> drain this body's reads) ----
    wait_all_ds(nx2);
    f32x4 se2;
    se2[0] = s[0] * nx1.e[0];
    se2[1] = s[1] * nx1.e[1];
    se2[2] = s[2] * nx1.e[2];
    se2[3] = s[3] * nx1.e[3];
    Pout.r2 = dot4(se2, nx2.a);
    Pout.bb = dot4(nx1.b, nx2.a);
    Pout.gg = dot4(nx1.k, nx2.a);
    Pout.yy = yp;

    sa = sa1;
  };

  // Prologue: fill ring (issue order = count order).
  for (int i = 0; i < 8; ++i) {
    stage(i, i);
    __builtin_amdgcn_sched_barrier(0);
  }
  // Slots 0,1 done: stages 2..7 = 12 newer load ops.
  asm volatile("s_waitcnt vmcnt(12)" ::: "memory");

  Buf B0, B1, B2, B3;
  lds_read(B0, 0);
  lds_read(B1, 1);
  asm volatile("s_waitcnt lgkmcnt(0)"
               : "+v"(B0.r), "+v"(B0.e), "+v"(B0.k), "+v"(B0.a), "+v"(B0.b),
                 "+v"(B0.vv), "+v"(B1.a), "+v"(B1.e), "+v"(B1.b), "+v"(B1.k));

  // sa_0 = S_init . a_0 (serial reduce, once)
  sa = row16_reduce(dot4(s, B0.a));

  // Prime partials for step 1: R2_1 = sum S_init∘e_0 · a_1, beta_1 = b_0·a_1,
  // gamma_1 = k_0·a_1 (raw partials; reduced at body 0 top). y_{-1} = 0.
  Quad PA, PB;
  {
    f32x4 se0;
    se0[0] = s[0] * B0.e[0];
    se0[1] = s[1] * B0.e[1];
    se0[2] = s[2] * B0.e[2];
    se0[3] = s[3] * B0.e[3];
    PA.r2 = dot4(se0, B1.a);
    PA.bb = dot4(B0.b, B1.a);
    PA.gg = dot4(B0.k, B1.a);
    PA.yy = 0.0f;
  }

  for (int t = 0; t < T_LEN; t += 8) {
    body(B0, B1, B2, PA, PB, t,     true );
    body(B1, B2, B3, PB, PA, t + 1, false);
    body(B2, B3, B0, PA, PB, t + 2, false);
    body(B3, B0, B1, PB, PA, t + 3, false);
    body(B0, B1, B2, PA, PB, t + 4, false);
    body(B1, B2, B3, PB, PA, t + 5, false);
    body(B2, B3, B0, PA, PB, t + 6, false);
    body(B3, B0, B1, PB, PA, t + 7, false);
  }

  // Epilogue: last body (t=2047) consumed PB (reducing y_2046 into lane 6)
  // and produced PA with PA.yy = y_2047 partial. Reduce it, place in lane 7,
  // flush the final batch (steps 2040..2047).
  {
    float y2047 = row16_reduce(PA.yy);
    ybatch = (cg == 7) ? y2047 : ybatch;
    if (cg < 8) {
      int voff = 2040 * (HD * 4) + ybo;
      asm volatile("global_store_dword %0, %1, %2"
                   :: "v"(voff), "v"(ybatch), "s"(X) : "memory");
    }
  }

  *(f32x4*)(SOUT + (size_t)h * DD * DD + row * DD + c0) = s;
}

extern "C" void kernel_launch(void* const* d_in, const int* in_sizes, int n_in,
                              void* d_out, int out_size, void* d_ws, size_t ws_size,
                              hipStream_t stream) {
  // setup_inputs order: seq_length, r, w, k, v, a, b, state2
  const float* r  = (const float*)d_in[1];
  const float* w  = (const float*)d_in[2];
  const float* k  = (const float*)d_in[3];
  const float* v  = (const float*)d_in[4];
  const float* a  = (const float*)d_in[5];
  const float* b  = (const float*)d_in[6];
  const float* s0 = (const float*)d_in[7];

  float* x    = (float*)d_out;                     // (T, H, 1, D)
  float* sout = x + (size_t)T_LEN * HD;            // (H, D, D)

  float* ew = (float*)d_ws;
  (void)ws_size; (void)in_sizes; (void)n_in;

  int n4 = T_LEN * HD / 4;
  hipLaunchKernelGGL(exp_kernel, dim3(1024), dim3(256), 0, stream,
                     (const float4*)w, (float4*)ew, n4);
  hipLaunchKernelGGL(wkv7_scan, dim3(1024), dim3(64), 0, stream,
                     r, ew, k, v, a, b, s0, x, sout);
}